// Round 1
// baseline (2547.832 us; speedup 1.0000x reference)
//
#include <hip/hip_runtime.h>

#define BATCH 4
#define NS    512
#define XS    1024
#define WID   64
#define DEPTH 6

__device__ __forceinline__ float fast_tanh(float v) {
    // tanh(v) = 1 - 2/(e^{2v}+1); __expf -> v_exp_f32, __fdividef -> v_rcp+mul
    float e = __expf(2.0f * v);
    return 1.0f - __fdividef(2.0f, e + 1.0f);
}

extern "C" __global__ __launch_bounds__(512, 2)
void neurop_kernel(const float* __restrict__ yu,   // (B, NS, 5): u0,u1,u2,y0,y1
                   const float* __restrict__ x,    // (B, XS, 2)
                   const float* __restrict__ W_in, // (1, 64)
                   const float* __restrict__ b_in, // (64)
                   const float* __restrict__ W_h,  // (6, 64, 64)
                   const float* __restrict__ b_h,  // (6, 64)
                   const float* __restrict__ W_out,// (64, 1)
                   const float* __restrict__ b_out,// (1)
                   float* __restrict__ out)        // (B, XS, 3)
{
    const int blk  = blockIdx.x;          // b*XS + xi
    const int b    = blk >> 10;           // /XS
    const int xi   = blk & (XS - 1);
    const int s    = threadIdx.x;         // sensor index, 0..511

    // query coords (uniform within block -> scalar loads)
    const float x0 = x[(b * XS + xi) * 2 + 0];
    const float x1 = x[(b * XS + xi) * 2 + 1];

    const float* yub = yu + (b * NS + s) * 5;
    const float y0 = yub[3];
    const float y1 = yub[4];
    const float d0 = x0 - y0;
    const float d1 = x1 - y1;
    const float r  = d0 * d0 + d1 * d1;

    float h[WID];
    #pragma unroll
    for (int j = 0; j < WID; ++j)
        h[j] = fmaf(r, W_in[j], b_in[j]);

    #pragma unroll 1
    for (int d = 0; d < DEPTH; ++d) {
        const float* __restrict__ Wl = W_h + d * WID * WID;
        const float* __restrict__ bl = b_h + d * WID;
        float hn[WID];
        #pragma unroll
        for (int j = 0; j < WID; ++j) hn[j] = bl[j];
        #pragma unroll
        for (int i = 0; i < WID; ++i) {
            const float hi = h[i];
            #pragma unroll
            for (int j = 0; j < WID; ++j)
                hn[j] = fmaf(hi, Wl[i * WID + j], hn[j]);
        }
        #pragma unroll
        for (int j = 0; j < WID; ++j)
            h[j] = fast_tanh(hn[j]) + h[j];
    }

    float k = b_out[0];
    #pragma unroll
    for (int j = 0; j < WID; ++j)
        k = fmaf(h[j], W_out[j], k);

    // multiply by u channels, reduce over the 512 sensors in this block
    float v0 = k * yub[0];
    float v1 = k * yub[1];
    float v2 = k * yub[2];

    #pragma unroll
    for (int off = 32; off > 0; off >>= 1) {
        v0 += __shfl_down(v0, off);
        v1 += __shfl_down(v1, off);
        v2 += __shfl_down(v2, off);
    }

    __shared__ float red[8][3];
    const int wave = threadIdx.x >> 6;
    const int lane = threadIdx.x & 63;
    if (lane == 0) {
        red[wave][0] = v0;
        red[wave][1] = v1;
        red[wave][2] = v2;
    }
    __syncthreads();
    if (threadIdx.x < 3) {
        float acc = 0.0f;
        #pragma unroll
        for (int wv = 0; wv < 8; ++wv) acc += red[wv][threadIdx.x];
        out[(b * XS + xi) * 3 + threadIdx.x] = acc * (1.0f / NS);
    }
}

extern "C" void kernel_launch(void* const* d_in, const int* in_sizes, int n_in,
                              void* d_out, int out_size, void* d_ws, size_t ws_size,
                              hipStream_t stream) {
    const float* yu    = (const float*)d_in[0];
    const float* x     = (const float*)d_in[1];
    const float* W_in  = (const float*)d_in[2];
    const float* b_in  = (const float*)d_in[3];
    const float* W_h   = (const float*)d_in[4];
    const float* b_h   = (const float*)d_in[5];
    const float* W_out = (const float*)d_in[6];
    const float* b_out = (const float*)d_in[7];
    float* out = (float*)d_out;

    dim3 grid(BATCH * XS);
    dim3 block(NS);
    hipLaunchKernelGGL(neurop_kernel, grid, block, 0, stream,
                       yu, x, W_in, b_in, W_h, b_h, W_out, b_out, out);
}

// Round 2
// 748.774 us; speedup vs baseline: 3.4027x; 3.4027x over previous
//
#include <hip/hip_runtime.h>

#define BATCH 4
#define NS    512
#define XS    1024

typedef float  f32x4  __attribute__((ext_vector_type(4)));
typedef __bf16 bf16x8 __attribute__((ext_vector_type(8)));

// LDS byte offsets (total 127360 <= 160K, 1 block/CU)
#define WFRAG_OFF 0          // 6*2*4*64*8 u16 = 49152 B  (B-fragments of W_h)
#define H_OFF     49152      // 8 waves * 64 rows * 72 pitch u16 = 73728 B
#define BH_OFF    122880     // 384 f32
#define WIN_OFF   124416     // 64 f32
#define BIN_OFF   124672     // 64 f32
#define WOUT_OFF  124928     // 64 f32
#define R_OFF     125184     // 512 f32
#define PART_OFF  127232     // 8*3 f32
#define BOUT_OFF  127328     // 1 f32
#define SMEM_BYTES 127360

__device__ __forceinline__ unsigned int f2bf(float f) {  // fp32 -> bf16 RNE
    unsigned int u = __float_as_uint(f);
    u += 0x7fffu + ((u >> 16) & 1u);
    return u >> 16;
}

extern "C" __global__ __launch_bounds__(512, 2)
void neurop_kernel(const float* __restrict__ yu, const float* __restrict__ x,
                   const float* __restrict__ W_in, const float* __restrict__ b_in,
                   const float* __restrict__ W_h, const float* __restrict__ b_h,
                   const float* __restrict__ W_out, const float* __restrict__ b_out,
                   float* __restrict__ out)
{
    extern __shared__ char smem[];
    unsigned short* wfrag = (unsigned short*)(smem + WFRAG_OFF);
    unsigned short* hstg  = (unsigned short*)(smem + H_OFF);
    float* bh_s   = (float*)(smem + BH_OFF);
    float* win_s  = (float*)(smem + WIN_OFF);
    float* bin_s  = (float*)(smem + BIN_OFF);
    float* wout_s = (float*)(smem + WOUT_OFF);
    float* r_s    = (float*)(smem + R_OFF);
    float* part_s = (float*)(smem + PART_OFF);
    float* bout_s = (float*)(smem + BOUT_OFF);

    const int t   = threadIdx.x;
    const int l   = t & 63;          // lane
    const int wv  = t >> 6;          // wave 0..7
    const int g   = l >> 4;          // 16-lane group 0..3
    const int c   = l & 15;          // col within fragment
    const int blk = blockIdx.x;      // b*XS + xi
    const int b   = blk >> 10;

    // ---- stage params into LDS ----
    if (t < 64) { win_s[t] = W_in[t]; bin_s[t] = b_in[t]; wout_s[t] = W_out[t]; }
    if (t < 384) bh_s[t] = b_h[t];
    if (t == 0)  bout_s[0] = b_out[0];
    // W_h as B-fragments: frag elem f = ((d*2+kf)*4+nf)*512 + lane*8 + j
    #pragma unroll 1
    for (int it = 0; it < 48; ++it) {
        int f  = t + it * 512;
        int d  = f >> 12;
        int kf = (f >> 11) & 1;
        int nf = (f >> 9) & 3;
        int ln = (f >> 3) & 63;
        int j  = f & 7;
        int k  = kf * 32 + (ln >> 4) * 8 + j;
        int n  = nf * 16 + (ln & 15);
        wfrag[f] = (unsigned short)f2bf(W_h[(d << 12) + (k << 6) + n]);
    }
    __syncthreads();

    // ---- r for this wave's 64 sensors (wave-private LDS, no barrier needed) ----
    const float x0 = x[(blk << 1) + 0];
    const float x1 = x[(blk << 1) + 1];
    {
        int s = wv * 64 + l;
        const float* yrow = yu + (b * NS + s) * 5;
        float d0 = x0 - yrow[3], d1 = x1 - yrow[4];
        r_s[s] = d0 * d0 + d1 * d1;
    }

    // ---- h0 = r*W_in + b_in, in C-fragment layout hc[mf][nf][reg] ----
    float hc[4][4][4];
    const int wbase = wv * 4608;     // u16 units (64 rows * 72 pitch)
    {
        float rr[4][4];
        #pragma unroll
        for (int mf = 0; mf < 4; ++mf) {
            f32x4 rv = *(const f32x4*)&r_s[wv * 64 + mf * 16 + g * 4];
            #pragma unroll
            for (int r = 0; r < 4; ++r) rr[mf][r] = rv[r];
        }
        #pragma unroll
        for (int nf = 0; nf < 4; ++nf) {
            float wi = win_s[nf * 16 + c];
            float bi = bin_s[nf * 16 + c];
            #pragma unroll
            for (int mf = 0; mf < 4; ++mf)
                #pragma unroll
                for (int r = 0; r < 4; ++r)
                    hc[mf][nf][r] = fmaf(rr[mf][r], wi, bi);
        }
    }

    // transpose C-frag (4 rows x 1 col per lane) -> row chunks, write bf16 to h stage
    auto writeFrag = [&](int mf, int nf, const float yv[4]) {
        float y0 = yv[0], y1 = yv[1], y2 = yv[2], y3 = yv[3];
        // 4x4 transpose across lanes (l&3) via 2-level butterfly
        float s0 = (l & 2) ? y0 : y2;
        float s1 = (l & 2) ? y1 : y3;
        s0 = __shfl_xor(s0, 2); s1 = __shfl_xor(s1, 2);
        if (l & 2) { y0 = s0; y1 = s1; } else { y2 = s0; y3 = s1; }
        float u0 = (l & 1) ? y0 : y1;
        float u1 = (l & 1) ? y2 : y3;
        u0 = __shfl_xor(u0, 1); u1 = __shfl_xor(u1, 1);
        if (l & 1) { y0 = u0; y2 = u1; } else { y1 = u0; y3 = u1; }
        unsigned int lo = f2bf(y0) | (f2bf(y1) << 16);
        unsigned int hi = f2bf(y2) | (f2bf(y3) << 16);
        int elem = wbase + (16 * mf + 4 * g + (l & 3)) * 72 + 16 * nf + (l & 12);
        *(uint2*)(hstg + elem) = make_uint2(lo, hi);
    };

    #pragma unroll
    for (int mf = 0; mf < 4; ++mf)
        #pragma unroll
        for (int nf = 0; nf < 4; ++nf)
            writeFrag(mf, nf, hc[mf][nf]);

    // ---- 6 residual layers: z = H@W + b; H += tanh(z) ----
    #pragma unroll 1
    for (int d = 0; d < 6; ++d) {
        bf16x8 a[4][2];
        #pragma unroll
        for (int mf = 0; mf < 4; ++mf)
            #pragma unroll
            for (int kf = 0; kf < 2; ++kf)
                a[mf][kf] = *(const bf16x8*)(hstg + wbase + (16 * mf + c) * 72 + kf * 32 + g * 8);
        bf16x8 bw[2][4];
        #pragma unroll
        for (int kf = 0; kf < 2; ++kf)
            #pragma unroll
            for (int nf = 0; nf < 4; ++nf)
                bw[kf][nf] = *(const bf16x8*)(wfrag + (((d * 2 + kf) * 4 + nf) * 64 + l) * 8);
        #pragma unroll
        for (int nf = 0; nf < 4; ++nf) {
            float bi = bh_s[d * 64 + nf * 16 + c];
            f32x4 z[4];
            #pragma unroll
            for (int mf = 0; mf < 4; ++mf) z[mf] = (f32x4){bi, bi, bi, bi};
            #pragma unroll
            for (int kf = 0; kf < 2; ++kf)
                #pragma unroll
                for (int mf = 0; mf < 4; ++mf)
                    z[mf] = __builtin_amdgcn_mfma_f32_16x16x32_bf16(a[mf][kf], bw[kf][nf], z[mf], 0, 0, 0);
            #pragma unroll
            for (int mf = 0; mf < 4; ++mf) {
                float yv[4];
                #pragma unroll
                for (int r = 0; r < 4; ++r) {
                    float e  = __expf(2.0f * z[mf][r]);          // inf-safe: tanh->1
                    float th = 1.0f - __fdividef(2.0f, e + 1.0f);
                    float nh = th + hc[mf][nf][r];
                    hc[mf][nf][r] = nh;
                    yv[r] = nh;
                }
                if (d < 5) writeFrag(mf, nf, yv);
            }
        }
    }

    // ---- k = h @ W_out + b_out; reduce over cols (16 lanes), then sensors ----
    float wo[4];
    #pragma unroll
    for (int nf = 0; nf < 4; ++nf) wo[nf] = wout_s[nf * 16 + c];
    float pk[4][4];
    #pragma unroll
    for (int mf = 0; mf < 4; ++mf)
        #pragma unroll
        for (int r = 0; r < 4; ++r) {
            float v = 0.f;
            #pragma unroll
            for (int nf = 0; nf < 4; ++nf) v = fmaf(hc[mf][nf][r], wo[nf], v);
            pk[mf][r] = v;
        }
    #pragma unroll
    for (int m = 1; m < 16; m <<= 1)
        #pragma unroll
        for (int mf = 0; mf < 4; ++mf)
            #pragma unroll
            for (int r = 0; r < 4; ++r)
                pk[mf][r] += __shfl_xor(pk[mf][r], m);
    const float bo = bout_s[0];

    if (c < 3) {   // lanes c=0..2 accumulate channel c over this wave's 16-row share
        float acc = 0.f;
        #pragma unroll
        for (int mf = 0; mf < 4; ++mf)
            #pragma unroll
            for (int r = 0; r < 4; ++r) {
                int srow = wv * 64 + mf * 16 + g * 4 + r;
                acc = fmaf(pk[mf][r] + bo, yu[(b * NS + srow) * 5 + c], acc);
            }
        acc += __shfl_xor(acc, 16);
        acc += __shfl_xor(acc, 32);
        if (g == 0) part_s[wv * 3 + c] = acc;
    }
    __syncthreads();
    if (t < 3) {
        float sum = 0.f;
        #pragma unroll
        for (int w = 0; w < 8; ++w) sum += part_s[w * 3 + t];
        out[blk * 3 + t] = sum * (1.0f / 512.0f);
    }
}

extern "C" void kernel_launch(void* const* d_in, const int* in_sizes, int n_in,
                              void* d_out, int out_size, void* d_ws, size_t ws_size,
                              hipStream_t stream) {
    const float* yu    = (const float*)d_in[0];
    const float* x     = (const float*)d_in[1];
    const float* W_in  = (const float*)d_in[2];
    const float* b_in  = (const float*)d_in[3];
    const float* W_h   = (const float*)d_in[4];
    const float* b_h   = (const float*)d_in[5];
    const float* W_out = (const float*)d_in[6];
    const float* b_out = (const float*)d_in[7];
    float* out = (float*)d_out;

    (void)hipFuncSetAttribute((const void*)neurop_kernel,
                              hipFuncAttributeMaxDynamicSharedMemorySize, SMEM_BYTES);
    hipLaunchKernelGGL(neurop_kernel, dim3(BATCH * XS), dim3(NS), SMEM_BYTES, stream,
                       yu, x, W_in, b_in, W_h, b_h, W_out, b_out, out);
}